// Round 1
// baseline (386.070 us; speedup 1.0000x reference)
//
#include <hip/hip_runtime.h>

typedef unsigned short u16;
typedef unsigned int u32;
typedef __attribute__((ext_vector_type(8))) short bf16x8;
typedef __attribute__((ext_vector_type(4))) float f32x4;
typedef __attribute__((ext_vector_type(8))) u16 u16x8;
typedef __attribute__((ext_vector_type(4))) u16 u16x4;

#define DEV __device__ __forceinline__

DEV u16 f2bf(float f) {
  u32 x = __float_as_uint(f);
  return (u16)((x + 0x7fffu + ((x >> 16) & 1u)) >> 16);  // RNE
}

// B=8 S=512 H=768 E=8 F=3072 K=2. fp32 I/O; bf16 MFMA internals.
// r8: both GEMMs -> BM=256 x BN=128 x BK=64, 8 waves, dbuf 96KB LDS,
// stage-2-tiles-ahead with counted s_waitcnt vmcnt(6) (never 0 in loop),
// raw s_barrier + setprio MFMA clusters (T3+T4+T5). Transposes all in prep.

// ---------- 128x64 tile transpose: fp32 src -> bf16 dst (256 thr) ----------
DEV void transpose_tile(const float* __restrict__ src, u16* __restrict__ dst,
                        int R, int C, int r0, int c0, int t, u16* tile /*128*68*/) {
#pragma unroll
  for (int i = 0; i < 8; ++i) {
    const int idx = i * 256 + t;
    const int row = idx >> 4, c4 = (idx & 15) * 4;
    const float4 v = *(const float4*)(src + (size_t)(r0 + row) * C + c0 + c4);
    u16x4 o; o[0] = f2bf(v.x); o[1] = f2bf(v.y); o[2] = f2bf(v.z); o[3] = f2bf(v.w);
    *(u16x4*)(tile + row * 68 + c4) = o;
  }
  __syncthreads();
#pragma unroll
  for (int i = 0; i < 4; ++i) {
    const int widx = i * 256 + t;
    const int c = widx >> 4, r8 = (widx & 15) * 8;
    u16x8 o;
#pragma unroll
    for (int j = 0; j < 8; ++j) o[j] = tile[(r8 + j) * 68 + c];
    *(u16x8*)(dst + (size_t)(c0 + c) * R + r0 + r8) = o;
  }
}

// ---------- prep: W1 tiles [0,2304); W2 tiles [2304,4608) (big ws);
//            convert+pool last 512 blocks ----------
__global__ void prep_kernel(const float* __restrict__ W1, u16* __restrict__ w1t,
                            const float* __restrict__ hidden, u16* __restrict__ hbf,
                            float* __restrict__ pooled,
                            const float* __restrict__ W2, u16* __restrict__ w2t,
                            int haveW2) {
  __shared__ __align__(16) u16 smem[128 * 68];
  const int bid = blockIdx.x, t = threadIdx.x;
  if (bid < 2304) {  // W1 [768,3072] -> [3072,768], 288 tiles/expert
    const int e = bid / 288, rem = bid % 288;
    const int r0 = (rem / 48) * 128, c0 = (rem % 48) * 64;
    transpose_tile(W1 + (size_t)e * 768 * 3072, w1t + (size_t)e * 768 * 3072,
                   768, 3072, r0, c0, t, smem);
    return;
  }
  if (haveW2 && bid < 4608) {  // W2 [3072,768] -> [768,3072]
    const int bb = bid - 2304;
    const int e = bb / 288, rem = bb % 288;
    const int r0 = (rem / 12) * 128, c0 = (rem % 12) * 64;
    transpose_tile(W2 + (size_t)e * 3072 * 768, w2t + (size_t)e * 3072 * 768,
                   3072, 768, r0, c0, t, smem);
    return;
  }
  if (t >= 192) return;  // convert role uses 192 lanes
  const int u = bid - (haveW2 ? 4608 : 2304);  // 512 units: 8 rows each
  const int b = u >> 6, chunk = u & 63;
  const size_t base = (size_t)b * 512 * 768 + (size_t)chunk * 8 * 768 + t * 4;
  float ax = 0.f, ay = 0.f, az = 0.f, aw = 0.f;
#pragma unroll
  for (int r = 0; r < 8; ++r) {
    const float4 v = *(const float4*)(hidden + base + r * 768);
    ax += v.x; ay += v.y; az += v.z; aw += v.w;
    u16x4 o; o[0] = f2bf(v.x); o[1] = f2bf(v.y); o[2] = f2bf(v.z); o[3] = f2bf(v.w);
    *(u16x4*)(hbf + base + r * 768) = o;
  }
  float* p = pooled + b * 768 + t * 4;
  atomicAdd(p + 0, ax); atomicAdd(p + 1, ay);
  atomicAdd(p + 2, az); atomicAdd(p + 3, aw);
}

// ---------- standalone transpose W2 (small-ws fallback path) ----------
__global__ void transpose_w2_kernel(const float* __restrict__ W2, u16* __restrict__ w2t) {
  __shared__ __align__(16) u16 smem[128 * 68];
  const int bid = blockIdx.x, t = threadIdx.x;
  const int e = bid / 288, rem = bid % 288;
  const int r0 = (rem / 12) * 128, c0 = (rem % 12) * 64;
  transpose_tile(W2 + (size_t)e * 3072 * 768, w2t + (size_t)e * 3072 * 768,
                 3072, 768, r0, c0, t, smem);
}

// ---------- router finalize ----------
__global__ void router_final_kernel(const float* __restrict__ pooled, const float* __restrict__ Wg,
                                    float* __restrict__ logits_out, int* __restrict__ sel,
                                    float* __restrict__ wsel) {
  __shared__ float l8[64];
  const int tid = threadIdx.x;
  const int b = tid >> 5, r = tid & 31, e = r >> 2, q = r & 3;
  float p = 0.f;
  for (int h = q * 192; h < q * 192 + 192; ++h) p += pooled[b * 768 + h] * Wg[h * 8 + e];
  p += __shfl_xor(p, 1);
  p += __shfl_xor(p, 2);
  if (q == 0) {
    const float lg = p * (1.f / 512.f);
    l8[b * 8 + e] = lg;
    logits_out[b * 8 + e] = lg;
  }
  __syncthreads();
  if (tid < 8) {
    const int bb = tid;
    float mx = -1e30f;
    for (int i = 0; i < 8; ++i) mx = fmaxf(mx, l8[bb * 8 + i]);
    float w[8], ssum = 0.f;
    for (int i = 0; i < 8; ++i) { w[i] = __expf(l8[bb * 8 + i] - mx); ssum += w[i]; }
    for (int i = 0; i < 8; ++i) w[i] /= ssum;
    int i0 = 0;
    for (int i = 1; i < 8; ++i) if (w[i] > w[i0]) i0 = i;   // first-occurrence ties
    int i1 = (i0 == 0) ? 1 : 0;
    for (int i = 0; i < 8; ++i) if (i != i0 && w[i] > w[i1]) i1 = i;
    sel[bb * 2 + 0] = i0; sel[bb * 2 + 1] = i1;
    wsel[bb * 2 + 0] = w[i0]; wsel[bb * 2 + 1] = w[i1];
  }
}

// ---------- pipelined GEMM core (512 thr / 8 waves, BM=256 BN=128 BK=64) ----
// LDS layout per buffer: A 256x64 (16384 u16) ++ B 128x64 (8192 u16) = 24576.
// Stage: linear LDS dest (wave-uniform base + lane*16B), XOR swizzle applied
// on the *global* source column (m201 pattern); reads un-swizzle with the
// same involution. 6 global_load_lds per tile (A:4, B:2).
template <int NCH>
DEV void stage_rows(const u16* __restrict__ g, int ld, int row0, int k0,
                    u16* l, int tid) {
  const int crow = tid >> 3;                       // 0..63
  const int swz = ((tid & 7) ^ (crow & 7)) * 8;    // crow&7 == row&7 (64|rows)
  const int wbase = tid & ~63;
  const u16* gb = g + (size_t)(row0 + crow) * ld + k0 + swz;
#pragma unroll
  for (int i = 0; i < NCH; ++i) {
    __builtin_amdgcn_global_load_lds(
        (const __attribute__((address_space(1))) void*)(gb + (size_t)i * 64 * ld),
        (__attribute__((address_space(3))) void*)(l + (i * 512 + wbase) * 8), 16, 0, 0);
  }
}

// One K-tile: 2 phases x 16 MFMA with setprio + raw barriers (no waitcnt!).
DEV void tile_phases(const u16* As, const u16* Bs, int wm, int wn, int mi, int kq,
                     f32x4 (&acc)[4][4]) {
  bf16x8 bfr[4][2];
#pragma unroll
  for (int nt = 0; nt < 4; ++nt) {
    const int row = wn + nt * 16 + mi;
#pragma unroll
    for (int ks = 0; ks < 2; ++ks) {
      const int slot = (ks * 4 + kq) ^ (row & 7);
      bfr[nt][ks] = *(const bf16x8*)(Bs + row * 64 + slot * 8);
    }
  }
  // phase 0: row-frags 0,1
  bf16x8 af0[2][2];
#pragma unroll
  for (int mt = 0; mt < 2; ++mt) {
    const int row = wm + mt * 16 + mi;
#pragma unroll
    for (int ks = 0; ks < 2; ++ks) {
      const int slot = (ks * 4 + kq) ^ (row & 7);
      af0[mt][ks] = *(const bf16x8*)(As + row * 64 + slot * 8);
    }
  }
  __builtin_amdgcn_s_setprio(1);
#pragma unroll
  for (int ks = 0; ks < 2; ++ks)
#pragma unroll
    for (int mt = 0; mt < 2; ++mt)
#pragma unroll
      for (int nt = 0; nt < 4; ++nt)
        acc[mt][nt] = __builtin_amdgcn_mfma_f32_16x16x32_bf16(af0[mt][ks], bfr[nt][ks], acc[mt][nt], 0, 0, 0);
  __builtin_amdgcn_s_setprio(0);
  __builtin_amdgcn_s_barrier();
  // phase 1: row-frags 2,3
  bf16x8 af1[2][2];
#pragma unroll
  for (int mt = 0; mt < 2; ++mt) {
    const int row = wm + (mt + 2) * 16 + mi;
#pragma unroll
    for (int ks = 0; ks < 2; ++ks) {
      const int slot = (ks * 4 + kq) ^ (row & 7);
      af1[mt][ks] = *(const bf16x8*)(As + row * 64 + slot * 8);
    }
  }
  __builtin_amdgcn_s_setprio(1);
#pragma unroll
  for (int ks = 0; ks < 2; ++ks)
#pragma unroll
    for (int mt = 0; mt < 2; ++mt)
#pragma unroll
      for (int nt = 0; nt < 4; ++nt)
        acc[mt + 2][nt] = __builtin_amdgcn_mfma_f32_16x16x32_bf16(af1[mt][ks], bfr[nt][ks], acc[mt + 2][nt], 0, 0, 0);
  __builtin_amdgcn_s_setprio(0);
  __builtin_amdgcn_s_barrier();  // all waves done reading this buffer
}

// ---------- GEMM1: 768 blocks, XCD x owns batch x (2 pairs x 48 tiles) ------
__global__ __launch_bounds__(512, 2) void gemm1_kernel(
    const u16* __restrict__ hbf, const u16* __restrict__ w1t,
    const float* __restrict__ b1, u16* __restrict__ hbuf,
    const int* __restrict__ sel, const float* __restrict__ wsel) {
  __shared__ __align__(16) u16 smem[2 * 24576];  // 96 KB
  const int tid = threadIdx.x, bid = blockIdx.x;
  const int xcd = bid & 7, slot = bid >> 3;       // 96 slots/XCD
  const int p = xcd * 2 + slot / 48;
  const int tt = slot % 48;
  const int m0 = (tt / 24) * 256, n0 = (tt % 24) * 128;
  const int b = p >> 1;
  const int e = sel[p];
  const float wgt = wsel[p];
  const u16* A = hbf + (size_t)b * 512 * 768;
  const u16* Bt = w1t + (size_t)e * 768 * 3072;
  const int lane = tid & 63, wv = tid >> 6;
  const int wm = (wv & 3) * 64, wn = (wv >> 2) * 64;  // 4M x 2N waves
  const int mi = lane & 15, kq = lane >> 4;

  f32x4 acc[4][4] = {};
  // prologue: tiles 0,1 (12 loads); vmcnt(6) => tile0 resident
  stage_rows<4>(A, 768, m0, 0, smem, tid);
  stage_rows<2>(Bt, 768, n0, 0, smem + 16384, tid);
  stage_rows<4>(A, 768, m0, 64, smem + 24576, tid);
  stage_rows<2>(Bt, 768, n0, 64, smem + 24576 + 16384, tid);
  asm volatile("s_waitcnt vmcnt(6)" ::: "memory");
  __builtin_amdgcn_s_barrier();

  constexpr int NT = 12;  // K=768
  for (int t = 0; t < NT; ++t) {
    const u16* As = smem + (t & 1) * 24576;
    tile_phases(As, As + 16384, wm, wn, mi, kq, acc);
    __builtin_amdgcn_sched_barrier(0);  // keep stage below the read barrier
    if (t + 2 < NT) {
      u16* d = smem + (t & 1) * 24576;  // freed by tile_phases' last barrier
      stage_rows<4>(A, 768, m0, (t + 2) * 64, d, tid);
      stage_rows<2>(Bt, 768, n0, (t + 2) * 64, d + 16384, tid);
      asm volatile("s_waitcnt vmcnt(6)" ::: "memory");  // tile t+1 resident
      __builtin_amdgcn_s_barrier();
    } else if (t + 1 < NT) {
      asm volatile("s_waitcnt vmcnt(0)" ::: "memory");  // pipeline tail
      __builtin_amdgcn_s_barrier();
    }
  }

  const float* b1e = b1 + e * 3072;
  u16* C = hbuf + (size_t)p * 512 * 3072;
#pragma unroll
  for (int nt = 0; nt < 4; ++nt) {
    const int col = n0 + wn + nt * 16 + mi;
    const float bias = b1e[col];
#pragma unroll
    for (int mt = 0; mt < 4; ++mt) {
#pragma unroll
      for (int r = 0; r < 4; ++r) {
        const int row = m0 + wm + mt * 16 + kq * 4 + r;  // C/D: col=lane&15, row=quad*4+reg
        const float x = acc[mt][nt][r] + bias;
        const float g = 0.5f * x * (1.f + erff(x * 0.70710678118654752f));  // exact GELU
        C[(size_t)row * 3072 + col] = f2bf(wgt * g);
      }
    }
  }
}

// ---------- GEMM2: split-K x8 (768 blocks, balanced 3 rounds), fp32 atomics -
// xcd=bid&7 (= batch), slot=bid>>3: ks=slot/12 (expert=ks>>2, kquarter=ks&3),
// tile=slot%12 (2m x 6n). ks==0 adds weighted bias (out pre-zeroed).
__global__ __launch_bounds__(512, 2) void gemm2_kernel(
    const u16* __restrict__ hbuf, const u16* __restrict__ w2t,
    const float* __restrict__ b2, float* __restrict__ out,
    const int* __restrict__ sel, const float* __restrict__ wsel) {
  __shared__ __align__(16) u16 smem[2 * 24576];  // 96 KB
  const int tid = threadIdx.x, bid = blockIdx.x;
  const int b = bid & 7, slot = bid >> 3;         // 96 slots/XCD
  const int ks = slot / 12, tt = slot % 12;
  const int m0 = (tt / 6) * 256, n0 = (tt % 6) * 128;
  const int kslot = ks >> 2;                      // expert 0/1
  const int kbase = (ks & 3) * 768;
  const int p = b * 2 + kslot;
  const int e = sel[p];
  const u16* A = hbuf + (size_t)p * 512 * 3072;
  const u16* Bt = w2t + (size_t)e * 768 * 3072;
  const int lane = tid & 63, wv = tid >> 6;
  const int wm = (wv & 3) * 64, wn = (wv >> 2) * 64;
  const int mi = lane & 15, kq = lane >> 4;

  f32x4 acc[4][4] = {};
  stage_rows<4>(A, 3072, m0, kbase, smem, tid);
  stage_rows<2>(Bt, 3072, n0, kbase, smem + 16384, tid);
  stage_rows<4>(A, 3072, m0, kbase + 64, smem + 24576, tid);
  stage_rows<2>(Bt, 3072, n0, kbase + 64, smem + 24576 + 16384, tid);
  asm volatile("s_waitcnt vmcnt(6)" ::: "memory");
  __builtin_amdgcn_s_barrier();

  constexpr int NT = 12;  // K=768 per split
  for (int t = 0; t < NT; ++t) {
    const u16* As = smem + (t & 1) * 24576;
    tile_phases(As, As + 16384, wm, wn, mi, kq, acc);
    __builtin_amdgcn_sched_barrier(0);
    if (t + 2 < NT) {
      u16* d = smem + (t & 1) * 24576;
      stage_rows<4>(A, 3072, m0, kbase + (t + 2) * 64, d, tid);
      stage_rows<2>(Bt, 3072, n0, kbase + (t + 2) * 64, d + 16384, tid);
      asm volatile("s_waitcnt vmcnt(6)" ::: "memory");
      __builtin_amdgcn_s_barrier();
    } else if (t + 1 < NT) {
      asm volatile("s_waitcnt vmcnt(0)" ::: "memory");
      __builtin_amdgcn_s_barrier();
    }
  }

  float* C = out + (size_t)b * 512 * 768;
  const float w0 = wsel[b * 2 + 0], w1 = wsel[b * 2 + 1];
  const float* b2e0 = b2 + sel[b * 2 + 0] * 768;
  const float* b2e1 = b2 + sel[b * 2 + 1] * 768;
#pragma unroll
  for (int nt = 0; nt < 4; ++nt) {
    const int col = n0 + wn + nt * 16 + mi;
    const float bias = (ks == 0) ? (w0 * b2e0[col] + w1 * b2e1[col]) : 0.f;
#pragma unroll
    for (int mt = 0; mt < 4; ++mt) {
#pragma unroll
      for (int r = 0; r < 4; ++r) {
        const int row = m0 + wm + mt * 16 + kq * 4 + r;
        atomicAdd(&C[(size_t)row * 768 + col], acc[mt][nt][r] + bias);
      }
    }
  }
}

extern "C" void kernel_launch(void* const* d_in, const int* in_sizes, int n_in,
                              void* d_out, int out_size, void* d_ws, size_t ws_size,
                              hipStream_t stream) {
  const float* hidden = (const float*)d_in[0];  // [8,512,768] fp32
  const float* Wg     = (const float*)d_in[1];  // [768,8]
  const float* W1     = (const float*)d_in[2];  // [8,768,3072]
  const float* b1     = (const float*)d_in[3];  // [8,3072]
  const float* W2     = (const float*)d_in[4];  // [8,3072,768]
  const float* b2     = (const float*)d_in[5];  // [8,768]
  float* out = (float*)d_out;                   // [8,512,768] ++ logits [8,8]

  char* ws = (char*)d_ws;
  int*   sel    = (int*)ws;
  float* wsel   = (float*)(ws + 64);
  float* pooled = (float*)(ws + 128);
  u16* hbf = (u16*)(ws + 32768);                         // 6.29 MB
  u16* w1t = hbf + (size_t)8 * 512 * 768;                // 37.75 MB
  const size_t WSZ = (size_t)8 * 3072 * 768;
  const bool big = ws_size >= (size_t)(32768 + 6291456 + 37748736 + 37748736 + 50331648);
  u16* w2t  = big ? (w1t + WSZ) : w1t;   // small ws: W2^T overlays W1^T after gemm1
  u16* hbuf = big ? (w2t + WSZ) : (w1t + WSZ);

  float* logits_out = out + (size_t)8 * 512 * 768;

  hipMemsetAsync(ws, 0, 32768, stream);                  // sel/wsel/pooled
  hipMemsetAsync(out, 0, (size_t)out_size * 4, stream);  // atomic accum base
  prep_kernel<<<big ? 5120 : 2816, 256, 0, stream>>>(W1, w1t, hidden, hbf, pooled,
                                                     W2, w2t, big ? 1 : 0);
  router_final_kernel<<<1, 256, 0, stream>>>(pooled, Wg, logits_out, sel, wsel);
  gemm1_kernel<<<768, 512, 0, stream>>>(hbf, w1t, b1, hbuf, sel, wsel);
  if (!big) transpose_w2_kernel<<<2304, 256, 0, stream>>>(W2, w2t);
  gemm2_kernel<<<768, 512, 0, stream>>>(hbuf, w2t, b2, out, sel, wsel);
}

// Round 3
// 346.502 us; speedup vs baseline: 1.1142x; 1.1142x over previous
//
#include <hip/hip_runtime.h>

typedef unsigned short u16;
typedef unsigned int u32;
typedef __attribute__((ext_vector_type(8))) short bf16x8;
typedef __attribute__((ext_vector_type(4))) float f32x4;
typedef __attribute__((ext_vector_type(8))) u16 u16x8;
typedef __attribute__((ext_vector_type(4))) u16 u16x4;

#define DEV __device__ __forceinline__

DEV u16 f2bf(float f) {
  u32 x = __float_as_uint(f);
  return (u16)((x + 0x7fffu + ((x >> 16) & 1u)) >> 16);  // RNE
}

// B=8 S=512 H=768 E=8 F=3072 K=2. fp32 I/O; bf16 MFMA internals.
// r9 (resubmit after broker timeout): 128x128/256thr geometry (2 blocks/CU,
// 64KB dbuf LDS), minimum 2-phase pipeline (T3+T4 recipe): STAGE(t+1) issued
// BEFORE compute(t), single vmcnt(0)+barrier per tile AFTER compute.
// gemm2 split-K x4. W2 transpose fused into gemm1 grid.

// ---------- 128x64 tile transpose: fp32 src -> bf16 dst (256 thr) ----------
DEV void transpose_tile(const float* __restrict__ src, u16* __restrict__ dst,
                        int R, int C, int r0, int c0, int t, u16* tile /*128*68*/) {
#pragma unroll
  for (int i = 0; i < 8; ++i) {
    const int idx = i * 256 + t;
    const int row = idx >> 4, c4 = (idx & 15) * 4;
    const float4 v = *(const float4*)(src + (size_t)(r0 + row) * C + c0 + c4);
    u16x4 o; o[0] = f2bf(v.x); o[1] = f2bf(v.y); o[2] = f2bf(v.z); o[3] = f2bf(v.w);
    *(u16x4*)(tile + row * 68 + c4) = o;
  }
  __syncthreads();
#pragma unroll
  for (int i = 0; i < 4; ++i) {
    const int widx = i * 256 + t;
    const int c = widx >> 4, r8 = (widx & 15) * 8;
    u16x8 o;
#pragma unroll
    for (int j = 0; j < 8; ++j) o[j] = tile[(r8 + j) * 68 + c];
    *(u16x8*)(dst + (size_t)(c0 + c) * R + r0 + r8) = o;
  }
}

// ---------- prep: [0,2304) transpose W1 tiles; [2304,2816) convert+pool ----------
__global__ void prep_kernel(const float* __restrict__ W1, u16* __restrict__ w1t,
                            const float* __restrict__ hidden, u16* __restrict__ hbf,
                            float* __restrict__ pooled) {
  __shared__ __align__(16) u16 smem[128 * 68];
  const int bid = blockIdx.x, t = threadIdx.x;
  if (bid < 2304) {  // W1 [768,3072] -> [3072,768], 288 tiles/expert
    const int e = bid / 288, rem = bid % 288;
    const int r0 = (rem / 48) * 128, c0 = (rem % 48) * 64;
    transpose_tile(W1 + (size_t)e * 768 * 3072, w1t + (size_t)e * 768 * 3072,
                   768, 3072, r0, c0, t, smem);
    return;
  }
  if (t >= 192) return;  // convert role uses 192 lanes
  const int u = bid - 2304;                 // 512 units: 8 rows each
  const int b = u >> 6, chunk = u & 63;
  const size_t base = (size_t)b * 512 * 768 + (size_t)chunk * 8 * 768 + t * 4;
  float ax = 0.f, ay = 0.f, az = 0.f, aw = 0.f;
#pragma unroll
  for (int r = 0; r < 8; ++r) {
    const float4 v = *(const float4*)(hidden + base + r * 768);
    ax += v.x; ay += v.y; az += v.z; aw += v.w;
    u16x4 o; o[0] = f2bf(v.x); o[1] = f2bf(v.y); o[2] = f2bf(v.z); o[3] = f2bf(v.w);
    *(u16x4*)(hbf + base + r * 768) = o;
  }
  float* p = pooled + b * 768 + t * 4;
  atomicAdd(p + 0, ax); atomicAdd(p + 1, ay);
  atomicAdd(p + 2, az); atomicAdd(p + 3, aw);
}

// ---------- standalone transpose W2 (small-ws fallback path) ----------
__global__ void transpose_w2_kernel(const float* __restrict__ W2, u16* __restrict__ w2t) {
  __shared__ __align__(16) u16 smem[128 * 68];
  const int bid = blockIdx.x, t = threadIdx.x;
  const int e = bid / 288, rem = bid % 288;
  const int r0 = (rem / 12) * 128, c0 = (rem % 12) * 64;
  transpose_tile(W2 + (size_t)e * 3072 * 768, w2t + (size_t)e * 3072 * 768,
                 3072, 768, r0, c0, t, smem);
}

// ---------- router finalize ----------
__global__ void router_final_kernel(const float* __restrict__ pooled, const float* __restrict__ Wg,
                                    float* __restrict__ logits_out, int* __restrict__ sel,
                                    float* __restrict__ wsel) {
  __shared__ float l8[64];
  const int tid = threadIdx.x;
  const int b = tid >> 5, r = tid & 31, e = r >> 2, q = r & 3;
  float p = 0.f;
  for (int h = q * 192; h < q * 192 + 192; ++h) p += pooled[b * 768 + h] * Wg[h * 8 + e];
  p += __shfl_xor(p, 1);
  p += __shfl_xor(p, 2);
  if (q == 0) {
    const float lg = p * (1.f / 512.f);
    l8[b * 8 + e] = lg;
    logits_out[b * 8 + e] = lg;
  }
  __syncthreads();
  if (tid < 8) {
    const int bb = tid;
    float mx = -1e30f;
    for (int i = 0; i < 8; ++i) mx = fmaxf(mx, l8[bb * 8 + i]);
    float w[8], ssum = 0.f;
    for (int i = 0; i < 8; ++i) { w[i] = __expf(l8[bb * 8 + i] - mx); ssum += w[i]; }
    for (int i = 0; i < 8; ++i) w[i] /= ssum;
    int i0 = 0;
    for (int i = 1; i < 8; ++i) if (w[i] > w[i0]) i0 = i;   // first-occurrence ties
    int i1 = (i0 == 0) ? 1 : 0;
    for (int i = 0; i < 8; ++i) if (i != i0 && w[i] > w[i1]) i1 = i;
    sel[bb * 2 + 0] = i0; sel[bb * 2 + 1] = i1;
    wsel[bb * 2 + 0] = w[i0]; wsel[bb * 2 + 1] = w[i1];
  }
}

// ---------- GEMM core: 128x128 tile, 256 thr, dbuf 64KB, 2-phase pipeline ----
// Per buffer: A 128x64 (8192 u16) ++ B 128x64 (8192 u16). Stage: linear LDS
// dest (wave-uniform base + lane*16B); XOR swizzle pre-applied on the global
// source column; reads un-swizzle with the same involution (round-0 proven).
DEV void stage_tile128(const u16* __restrict__ g, int ld, int row0, int k0,
                       u16* l, int tid) {
  const int crow = tid >> 3;                       // 0..31
  const int swz = ((tid & 7) ^ (crow & 7)) * 8;
  const int wbase = tid & ~63;
  const u16* gb = g + (size_t)(row0 + crow) * ld + k0 + swz;
#pragma unroll
  for (int i = 0; i < 4; ++i) {
    __builtin_amdgcn_global_load_lds(
        (const __attribute__((address_space(1))) void*)(gb + (size_t)i * 32 * ld),
        (__attribute__((address_space(3))) void*)(l + (i * 256 + wbase) * 8), 16, 0, 0);
  }
}

// One K-tile of compute: load all 16 frags, then one setprio MFMA cluster x32.
DEV void tile_compute(const u16* As, const u16* Bs, int wm, int wn, int mi, int kq,
                      f32x4 (&acc)[4][4]) {
  bf16x8 af[4][2], bfr[4][2];
#pragma unroll
  for (int mt = 0; mt < 4; ++mt) {
    const int row = wm + mt * 16 + mi;
#pragma unroll
    for (int ks = 0; ks < 2; ++ks) {
      const int slot = (ks * 4 + kq) ^ (row & 7);
      af[mt][ks] = *(const bf16x8*)(As + row * 64 + slot * 8);
    }
  }
#pragma unroll
  for (int nt = 0; nt < 4; ++nt) {
    const int row = wn + nt * 16 + mi;
#pragma unroll
    for (int ks = 0; ks < 2; ++ks) {
      const int slot = (ks * 4 + kq) ^ (row & 7);
      bfr[nt][ks] = *(const bf16x8*)(Bs + row * 64 + slot * 8);
    }
  }
  __builtin_amdgcn_s_setprio(1);
#pragma unroll
  for (int ks = 0; ks < 2; ++ks)
#pragma unroll
    for (int mt = 0; mt < 4; ++mt)
#pragma unroll
      for (int nt = 0; nt < 4; ++nt)
        acc[mt][nt] = __builtin_amdgcn_mfma_f32_16x16x32_bf16(af[mt][ks], bfr[nt][ks], acc[mt][nt], 0, 0, 0);
  __builtin_amdgcn_s_setprio(0);
}

// ---------- GEMM1 (+fused W2 transpose when nT>0) ----------
// gemm part: xcd=bid&7, slot=bid>>3 (0..191), p = xcd*2 + slot/96, t=slot%96,
// m0=(t/24)*128, n0=(t%24)*128.
__global__ __launch_bounds__(256, 2) void gemm1_kernel(
    const u16* __restrict__ hbf, const u16* __restrict__ w1t,
    const float* __restrict__ b1, u16* __restrict__ hbuf,
    const int* __restrict__ sel, const float* __restrict__ wsel,
    const float* __restrict__ W2, u16* __restrict__ w2t, int nT) {
  __shared__ __align__(16) u16 smem[2 * 16384];  // 64 KB (dbuf A+B)
  const int tid = threadIdx.x;
  int bid = blockIdx.x;
  if (bid < nT) {  // W2 [3072,768] -> [768,3072]
    const int e = bid / 288, rem = bid % 288;
    const int r0 = (rem / 12) * 128, c0 = (rem % 12) * 64;
    transpose_tile(W2 + (size_t)e * 3072 * 768, w2t + (size_t)e * 3072 * 768,
                   3072, 768, r0, c0, tid, smem);
    return;
  }
  bid -= nT;
  const int xcd = bid & 7, slot = bid >> 3;
  const int p = xcd * 2 + slot / 96;        // XCD x owns batch x's 2 pairs
  const int tt = slot % 96;
  const int m0 = (tt / 24) * 128, n0 = (tt % 24) * 128;
  const int b = p >> 1;
  const int e = sel[p];
  const float wgt = wsel[p];
  const u16* A = hbf + (size_t)b * 512 * 768;
  const u16* Bt = w1t + (size_t)e * 768 * 3072;
  const int lane = tid & 63, wv = tid >> 6;
  const int wm = (wv >> 1) * 64, wn = (wv & 1) * 64;
  const int mi = lane & 15, kq = lane >> 4;

  f32x4 acc[4][4] = {};
  // prologue: stage tile 0, drain, barrier
  stage_tile128(A, 768, m0, 0, smem, tid);
  stage_tile128(Bt, 768, n0, 0, smem + 8192, tid);
  asm volatile("s_waitcnt vmcnt(0)" ::: "memory");
  __builtin_amdgcn_s_barrier();

  constexpr int NT12 = 12;  // K=768
  for (int t = 0; t < NT12; ++t) {
    u16* cur = smem + (t & 1) * 16384;
    u16* nxt = smem + ((t + 1) & 1) * 16384;
    if (t + 1 < NT12) {  // issue next-tile stage BEFORE compute
      stage_tile128(A, 768, m0, (t + 1) * 64, nxt, tid);
      stage_tile128(Bt, 768, n0, (t + 1) * 64, nxt + 8192, tid);
    }
    __builtin_amdgcn_sched_barrier(0);
    tile_compute(cur, cur + 8192, wm, wn, mi, kq, acc);
    if (t + 1 < NT12) {  // one drain+barrier per tile, AFTER compute
      asm volatile("s_waitcnt vmcnt(0)" ::: "memory");
      __builtin_amdgcn_s_barrier();
    }
  }

  const float* b1e = b1 + e * 3072;
  u16* C = hbuf + (size_t)p * 512 * 3072;
#pragma unroll
  for (int nt = 0; nt < 4; ++nt) {
    const int col = n0 + wn + nt * 16 + mi;
    const float bias = b1e[col];
#pragma unroll
    for (int mt = 0; mt < 4; ++mt) {
#pragma unroll
      for (int r = 0; r < 4; ++r) {
        const int row = m0 + wm + mt * 16 + kq * 4 + r;  // C/D: col=lane&15, row=quad*4+reg
        const float x = acc[mt][nt][r] + bias;
        const float g = 0.5f * x * (1.f + erff(x * 0.70710678118654752f));  // exact GELU
        C[(size_t)row * 3072 + col] = f2bf(wgt * g);
      }
    }
  }
}

// ---------- GEMM2 split-K x4, XCD-remapped, fp32 atomics ----------
// grid 768: xcd=bid&7 (= batch), slot=bid>>3 (0..95), ks=slot/24, t=slot%24,
// m=t/6, n=t%6. ks==0 adds weighted bias (out pre-zeroed).
__global__ __launch_bounds__(256, 2) void gemm2_kernel(
    const u16* __restrict__ hbuf, const u16* __restrict__ w2t,
    const float* __restrict__ b2, float* __restrict__ out,
    const int* __restrict__ sel, const float* __restrict__ wsel) {
  __shared__ __align__(16) u16 smem[2 * 16384];  // 64 KB
  const int bid = blockIdx.x, tid = threadIdx.x;
  const int b = bid & 7, slot = bid >> 3;
  const int ks = slot / 24, tt = slot % 24;
  const int m0 = (tt / 6) * 128, n0 = (tt % 6) * 128;
  const int kslot = ks >> 1;
  const int e = sel[b * 2 + kslot];
  const u16* A = hbuf + (size_t)(b * 2 + kslot) * 512 * 3072;
  const u16* Bt = w2t + (size_t)e * 768 * 3072;
  const int kbase = (ks & 1) * 1536;
  const int lane = tid & 63, wv = tid >> 6;
  const int wm = (wv >> 1) * 64, wn = (wv & 1) * 64;
  const int mi = lane & 15, kq = lane >> 4;

  f32x4 acc[4][4] = {};
  stage_tile128(A, 3072, m0, kbase, smem, tid);
  stage_tile128(Bt, 3072, n0, kbase, smem + 8192, tid);
  asm volatile("s_waitcnt vmcnt(0)" ::: "memory");
  __builtin_amdgcn_s_barrier();

  constexpr int NT24 = 24;  // K=1536 per split
  for (int t = 0; t < NT24; ++t) {
    u16* cur = smem + (t & 1) * 16384;
    u16* nxt = smem + ((t + 1) & 1) * 16384;
    if (t + 1 < NT24) {
      stage_tile128(A, 3072, m0, kbase + (t + 1) * 64, nxt, tid);
      stage_tile128(Bt, 3072, n0, kbase + (t + 1) * 64, nxt + 8192, tid);
    }
    __builtin_amdgcn_sched_barrier(0);
    tile_compute(cur, cur + 8192, wm, wn, mi, kq, acc);
    if (t + 1 < NT24) {
      asm volatile("s_waitcnt vmcnt(0)" ::: "memory");
      __builtin_amdgcn_s_barrier();
    }
  }

  float* C = out + (size_t)b * 512 * 768;
  const float w0 = wsel[b * 2 + 0], w1 = wsel[b * 2 + 1];
  const float* b2e0 = b2 + sel[b * 2 + 0] * 768;
  const float* b2e1 = b2 + sel[b * 2 + 1] * 768;
#pragma unroll
  for (int nt = 0; nt < 4; ++nt) {
    const int col = n0 + wn + nt * 16 + mi;
    const float bias = (ks == 0) ? (w0 * b2e0[col] + w1 * b2e1[col]) : 0.f;
#pragma unroll
    for (int mt = 0; mt < 4; ++mt) {
#pragma unroll
      for (int r = 0; r < 4; ++r) {
        const int row = m0 + wm + mt * 16 + kq * 4 + r;
        atomicAdd(&C[(size_t)row * 768 + col], acc[mt][nt][r] + bias);
      }
    }
  }
}

extern "C" void kernel_launch(void* const* d_in, const int* in_sizes, int n_in,
                              void* d_out, int out_size, void* d_ws, size_t ws_size,
                              hipStream_t stream) {
  const float* hidden = (const float*)d_in[0];  // [8,512,768] fp32
  const float* Wg     = (const float*)d_in[1];  // [768,8]
  const float* W1     = (const float*)d_in[2];  // [8,768,3072]
  const float* b1     = (const float*)d_in[3];  // [8,3072]
  const float* W2     = (const float*)d_in[4];  // [8,3072,768]
  const float* b2     = (const float*)d_in[5];  // [8,768]
  float* out = (float*)d_out;                   // [8,512,768] ++ logits [8,8]

  char* ws = (char*)d_ws;
  int*   sel    = (int*)ws;
  float* wsel   = (float*)(ws + 64);
  float* pooled = (float*)(ws + 128);
  u16* hbf = (u16*)(ws + 32768);                         // 6.29 MB
  u16* w1t = hbf + (size_t)8 * 512 * 768;                // 37.75 MB
  const size_t WSZ = (size_t)8 * 3072 * 768;
  const bool big = ws_size >= (size_t)(32768 + 6291456 + 37748736 + 37748736 + 50331648);
  u16* w2t  = big ? (w1t + WSZ) : w1t;   // small ws: W2^T overlays W1^T after gemm1
  u16* hbuf = big ? (w2t + WSZ) : (w1t + WSZ);

  float* logits_out = out + (size_t)8 * 512 * 768;

  hipMemsetAsync(ws, 0, 32768, stream);                  // sel/wsel/pooled
  hipMemsetAsync(out, 0, (size_t)out_size * 4, stream);  // atomic accum base
  prep_kernel<<<2816, 256, 0, stream>>>(W1, w1t, hidden, hbf, pooled);
  router_final_kernel<<<1, 256, 0, stream>>>(pooled, Wg, logits_out, sel, wsel);
  if (big) {
    gemm1_kernel<<<2304 + 1536, 256, 0, stream>>>(hbf, w1t, b1, hbuf, sel, wsel, W2, w2t, 2304);
  } else {
    gemm1_kernel<<<1536, 256, 0, stream>>>(hbf, w1t, b1, hbuf, sel, wsel, W2, w2t, 0);
    transpose_w2_kernel<<<2304, 256, 0, stream>>>(W2, w2t);
  }
  gemm2_kernel<<<768, 256, 0, stream>>>(hbuf, w2t, b2, out, sel, wsel);
}